// Round 8
// baseline (377.762 us; speedup 1.0000x reference)
//
#include <hip/hip_runtime.h>
#include <cstdint>
#include <cstddef>

// Problem constants (match reference)
constexpr int CB = 2;      // batch
constexpr int CS = 2048;   // seq
constexpr int CD = 1024;   // model dim
constexpr int CH = 16;     // heads
constexpr int CDK = 64;    // head dim
constexpr float NEGV = -1000000000.0f;
// q pre-scale: (1/sqrt(DK)) / ln2  -> softmax computed via exp2 (HW op):
// exp(q.k/8) == exp2(q.k * QSCALE) with QSCALE folded into the q projection.
constexpr float QSCALE = 0.18033688011112042f;

typedef __bf16 bf16x8 __attribute__((ext_vector_type(8)));
typedef float f32x4 __attribute__((ext_vector_type(4)));
typedef unsigned short u16x8 __attribute__((ext_vector_type(8)));
typedef unsigned short u16x4 __attribute__((ext_vector_type(4)));

static __device__ __forceinline__ unsigned short f2bf(float x) {
  unsigned int u = __float_as_uint(x);
  u += 0x7fffu + ((u >> 16) & 1u);   // round-to-nearest-even
  return (unsigned short)(u >> 16);
}
static __device__ __forceinline__ bf16x8 bc8(u16x8 u) {
  return __builtin_bit_cast(bf16x8, u);
}
static __device__ __forceinline__ f32x4 mfma16(bf16x8 a, bf16x8 b, f32x4 c) {
  return __builtin_amdgcn_mfma_f32_16x16x32_bf16(a, b, c, 0, 0, 0);
}

// ---------------------------------------------------------------- cvt f32->bf16 (all 7 tensors, one launch)
struct CvtArgs {
  const float* src[7];
  unsigned short* dst[7];
  int n4[7];
};

__global__ __launch_bounds__(256) void cvt_all(CvtArgs a) {
  const int r = blockIdx.y;
  const float* __restrict__ in = a.src[r];
  unsigned short* __restrict__ out = a.dst[r];
  const int n4 = a.n4[r];
  const int stride = gridDim.x * 256;
  for (int i = blockIdx.x * 256 + threadIdx.x; i < n4; i += stride) {
    float4 v = reinterpret_cast<const float4*>(in)[i];
    u16x4 o;
    o[0] = f2bf(v.x); o[1] = f2bf(v.y); o[2] = f2bf(v.z); o[3] = f2bf(v.w);
    reinterpret_cast<u16x4*>(out)[i] = o;
  }
}

// ---------------------------------------------------------------- GEMM core (m97 recipe, templated BN)
// BM=128, BN in {64,128}, BK=32, 4 waves. global_load_lds(16B) staging into
// linear LDS; SOURCE 16B-slot XOR-swizzled (rule 21) matching the frag-read
// swizzle. One barrier per K-step, double-buffered.
// X[M,K], W[N,K] bf16 row-major (NT). K=1024 fixed.
constexpr int GK = 1024, GNT = GK / 32;

struct QKVArgs {
  const unsigned short* X[3];
  const unsigned short* W[3];
  const float* bias[3];
  unsigned short* out[3];
  float osc[3];
};

template <int BN, typename EPI>
__device__ __forceinline__ void gemm_body(const unsigned short* __restrict__ X,
                                          const unsigned short* __restrict__ Wt,
                                          EPI epi) {
  __shared__ unsigned short lA[2][128 * 32];
  __shared__ unsigned short lB[2][BN * 32];
  const int tid = threadIdx.x, lane = tid & 63, wid = tid >> 6;
  const int fr = lane & 15, fc = lane >> 4;
  const int mbase = blockIdx.y * 128, nbase = blockIdx.x * BN;
  const int wm = (wid & 1) * 64, wn = (wid >> 1) * (BN / 2);

  // per-wave staging: contiguous 1KB LDS chunks (16 rows x 64B), lane l covers
  // row l>>2, 16B slot (l&3) XOR-swizzled at the SOURCE (read applies same XOR).
  const int srow = lane >> 2;
  const int sslot = (lane & 3) ^ (srow & 3);
  const int cA = wid * 2;  // wave's A chunk base (2 chunks of 16 rows)
  const unsigned short* a0 = X + (size_t)(mbase + cA * 16 + srow) * GK + sslot * 8;
  const unsigned short* b0;
  if constexpr (BN == 128) b0 = Wt + (size_t)(nbase + cA * 16 + srow) * GK + sslot * 8;
  else                     b0 = Wt + (size_t)(nbase + wid * 16 + srow) * GK + sslot * 8;

  auto stage = [&](int buf, int k0) {
#pragma unroll
    for (int c = 0; c < 2; ++c)
      __builtin_amdgcn_global_load_lds(
          (const __attribute__((address_space(1))) void*)(a0 + (size_t)c * 16 * GK + k0),
          (__attribute__((address_space(3))) void*)((char*)&lA[buf][0] + (cA + c) * 1024), 16, 0, 0);
    if constexpr (BN == 128) {
#pragma unroll
      for (int c = 0; c < 2; ++c)
        __builtin_amdgcn_global_load_lds(
            (const __attribute__((address_space(1))) void*)(b0 + (size_t)c * 16 * GK + k0),
            (__attribute__((address_space(3))) void*)((char*)&lB[buf][0] + (cA + c) * 1024), 16, 0, 0);
    } else {
      __builtin_amdgcn_global_load_lds(
          (const __attribute__((address_space(1))) void*)(b0 + k0),
          (__attribute__((address_space(3))) void*)((char*)&lB[buf][0] + wid * 1024), 16, 0, 0);
    }
  };

  constexpr int NJ = BN / 32;
  f32x4 acc[4][NJ] = {};
  stage(0, 0);
  __syncthreads();
  for (int t = 0; t < GNT; ++t) {
    if (t + 1 < GNT) stage((t + 1) & 1, (t + 1) * 32);
    const int buf = t & 1;
    bf16x8 af[4], bfv[NJ];
#pragma unroll
    for (int i = 0; i < 4; ++i) {
      const int row = wm + i * 16 + fr;
      af[i] = bc8(*reinterpret_cast<const u16x8*>(&lA[buf][row * 32 + ((fc ^ (row & 3)) * 8)]));
    }
#pragma unroll
    for (int j = 0; j < NJ; ++j) {
      const int row = wn + j * 16 + fr;
      bfv[j] = bc8(*reinterpret_cast<const u16x8*>(&lB[buf][row * 32 + ((fc ^ (row & 3)) * 8)]));
    }
#pragma unroll
    for (int i = 0; i < 4; ++i)
#pragma unroll
      for (int j = 0; j < NJ; ++j)
        acc[i][j] = mfma16(af[i], bfv[j], acc[i][j]);
    __syncthreads();
  }

#pragma unroll
  for (int j = 0; j < NJ; ++j) {
    const int colb = nbase + wn + j * 16 + fr;
#pragma unroll
    for (int i = 0; i < 4; ++i) {
#pragma unroll
      for (int r = 0; r < 4; ++r) {
        const int rowb = mbase + wm + i * 16 + fc * 4 + r;
        epi(rowb, colb, acc[i][j][r]);
      }
    }
  }
}

// Output layouts:
//  z=0 q : bf16 [bh][s][dk], pre-scaled by QSCALE
//  z=1 k : bf16 frag-tiled [bh][kt][g*2+half][lane*8+z]  (QK A-frags: rows=keys,
//          slots=dk, lane = fr2+16*fc2, identical A/B frag layout)
//  z=2 v : bf16 slot-permuted frag tiles [bh][kt][c*4+g][lane*8+zv] matching the
//          in-register P packing: within a 32-key chunk c, slot s=fc*8+z holds
//          key k32 = 16*(z>>2) + fc*4 + (z&3); lane = (d&15) + 16*fc.
__global__ __launch_bounds__(256, 3) void gemm_qkv(QKVArgs a) {
  const int z = blockIdx.z;
  const float* bias = a.bias[z];
  unsigned short* out = a.out[z];
  const float osc = a.osc[z];
  gemm_body<128>(a.X[z], a.W[z], [&](int rowb, int colb, float av) {
    const float v = (av + bias[colb]) * osc;
    const int bb = rowb >> 11, sr = rowb & (CS - 1);
    const int hh = colb >> 6, cc = colb & (CDK - 1);
    const size_t bh = (size_t)bb * CH + hh;
    if (z == 0) {
      out[(bh * CS + sr) * CDK + cc] = f2bf(v);
    } else if (z == 1) {
      const int kt = sr >> 6, ww = sr & 63, g = ww >> 4, fr2 = ww & 15;
      const int half = cc >> 5, fc2 = (cc >> 3) & 3, zz = cc & 7;
      out[(bh * 256 + kt * 8 + g * 2 + half) * 512 + (fc2 * 16 + fr2) * 8 + zz] = f2bf(v);
    } else {
      const int kt = sr >> 6, kk = sr & 63;
      const int c = kk >> 5, k32 = kk & 31;
      const int fcv = (k32 >> 2) & 3;              // slot group
      const int zv = ((k32 >> 4) << 2) | (k32 & 3);  // element within lane
      const int g = cc >> 4, fr2 = cc & 15;
      out[(bh * 256 + kt * 8 + c * 4 + g) * 512 + (fr2 + 16 * fcv) * 8 + zv] = f2bf(v);
    }
  });
}

__global__ __launch_bounds__(256) void gemm_fc(const unsigned short* __restrict__ X,
                                               const unsigned short* __restrict__ Wt,
                                               const float* __restrict__ bias,
                                               float* __restrict__ out) {
  gemm_body<64>(X, Wt, [&](int rowb, int colb, float av) {
    out[(size_t)rowb * CD + colb] = av + bias[colb];
  });
}

// ---------------------------------------------------------------- attention pass 1
// Denominators only, K split 4 ways. One block (4 waves) per (b,h,16-query
// group); wave kq=wid sums exp2 over K-tiles [kq*8, kq*8+8) for all 16 queries
// and writes its partial row-sum to lsum[kq][bh][q] (pure writes, no atomics:
// pass 2 adds the 4 partials -> deterministic). Swapped QK (mfma(K,Q)) makes
// the row sum per-lane scalar; tiny register footprint -> 5 waves/SIMD.
__global__ __launch_bounds__(256, 5) void attn_pass1(const unsigned short* __restrict__ qh,
                                                     const unsigned short* __restrict__ kT,
                                                     const unsigned char* __restrict__ mask,
                                                     float* __restrict__ lsum) {
  const int tid = threadIdx.x, lane = tid & 63, kq = tid >> 6;
  // bijective XCD swizzle over 4096 blocks: each XCD gets 512 consecutive swz
  const int bid = blockIdx.x;
  const int swz = (bid & 7) * 512 + (bid >> 3);
  const int q16 = swz & 127, hh = (swz >> 7) & 15, b = swz >> 11;
  const int bh = b * CH + hh;
  const int qw = q16 * 16;
  const int fr = lane & 15, fc = lane >> 4;

  const unsigned short* qp = qh + ((size_t)bh * CS + qw + fr) * CDK + fc * 8;
  const bf16x8 aq0 = bc8(*reinterpret_cast<const u16x8*>(qp));
  const bf16x8 aq1 = bc8(*reinterpret_cast<const u16x8*>(qp + 32));

  const unsigned short* kbase = kT + (size_t)bh * 131072 + lane * 8;
  const int kt0 = kq * 8;

  // dirty prescan for this wave's 8 tiles (16 query rows x 64 keys each)
  const unsigned char* mrow = mask + ((size_t)b * CS + qw + (lane >> 2)) * CS + (lane & 3) * 16;
  unsigned int dirty = 0;
#pragma unroll
  for (int i = 0; i < 8; ++i) {
    const uint4 mv = *reinterpret_cast<const uint4*>(mrow + (kt0 + i) * 64);
    if (__ballot((mv.x | mv.y | mv.z | mv.w) != 0)) dirty |= (1u << i);
  }

  u16x8 kreg[8];
  auto loadK = [&](int kt) {
    const unsigned short* p = kbase + (size_t)kt * 4096;
#pragma unroll
    for (int f = 0; f < 8; ++f) kreg[f] = *reinterpret_cast<const u16x8*>(p + f * 512);
  };
  const unsigned char* mq = mask + ((size_t)b * CS + qw + fr) * CS + fc * 4;

  float ls = 0.f;
  loadK(kt0);
  for (int i = 0; i < 8; ++i) {
    const int kt = kt0 + i;
    f32x4 sf[4];
#pragma unroll
    for (int g = 0; g < 4; ++g) {
      f32x4 a = {0.f, 0.f, 0.f, 0.f};
      a = mfma16(bc8(kreg[2 * g]), aq0, a);
      a = mfma16(bc8(kreg[2 * g + 1]), aq1, a);
      sf[g] = a;
    }
    loadK(i + 1 < 8 ? kt + 1 : kt0);  // prefetch (WAR orders after MFMAs)
    if ((dirty >> i) & 1u) {
#pragma unroll
      for (int g = 0; g < 4; ++g) {
        const uchar4 m4 = *reinterpret_cast<const uchar4*>(mq + kt * 64 + g * 16);
        if (m4.x) sf[g][0] = NEGV;
        if (m4.y) sf[g][1] = NEGV;
        if (m4.z) sf[g][2] = NEGV;
        if (m4.w) sf[g][3] = NEGV;
      }
    }
#pragma unroll
    for (int g = 0; g < 4; ++g)
      ls += (exp2f(sf[g][0]) + exp2f(sf[g][1])) + (exp2f(sf[g][2]) + exp2f(sf[g][3]));
  }
  ls += __shfl_xor(ls, 16);
  ls += __shfl_xor(ls, 32);
  if (lane < 16) lsum[((size_t)kq * 32 + bh) * CS + qw + fr] = ls;
}

// ---------------------------------------------------------------- attention pass 2
// Barrier-free, LDS-free. One block (4 independent waves) per (b,h,64q tile);
// wave owns 16 queries. SWAPPED QK^T: lane (fr,fc) reg (g,r) = P[q=fr][k =
// g*16 + fc*4 + r]. Denominator read from pass 1's 4 partials. attnw stored
// directly (nontemporal, full 64B lines); PV A-frag packed in-register with
// v_cvt_pk_bf16_f32 against slot-permuted V tiles.
__global__ __launch_bounds__(256, 3) void attn_pass2(const unsigned short* __restrict__ qh,
                                                     const unsigned short* __restrict__ kT,
                                                     const unsigned short* __restrict__ vT,
                                                     const unsigned char* __restrict__ mask,
                                                     const float* __restrict__ lsum,
                                                     float* __restrict__ attnw,
                                                     unsigned short* __restrict__ attn_pre) {
  const int tid = threadIdx.x, lane = tid & 63, wid = tid >> 6;
  // bijective XCD swizzle: each XCD gets 128 consecutive swz = 4 whole heads
  const int bid = blockIdx.x;
  const int swz = (bid & 7) * 128 + (bid >> 3);
  const int qt = swz & 31, hh = (swz >> 5) & 15, b = swz >> 9;
  const int bh = b * CH + hh;
  const int qw = qt * 64 + wid * 16;
  const int fr = lane & 15, fc = lane >> 4;

  // q fragments (B-operand): row = fr (query), dk = fc*8.. per 32-chunk
  const unsigned short* qp = qh + ((size_t)bh * CS + qw + fr) * CDK + fc * 8;
  const bf16x8 aq0 = bc8(*reinterpret_cast<const u16x8*>(qp));
  const bf16x8 aq1 = bc8(*reinterpret_cast<const u16x8*>(qp + 32));

  const unsigned short* kbase = kT + (size_t)bh * 131072 + lane * 8;
  const unsigned short* vbase = vT + (size_t)bh * 131072 + lane * 8;

  // denominator: sum of the 4 K-quarter partials (fixed order -> deterministic)
  float ls = 0.f;
#pragma unroll
  for (int kq = 0; kq < 4; ++kq) ls += lsum[((size_t)kq * 32 + bh) * CS + qw + fr];
  const float linv = 1.0f / ls;

  // ---------------- mask prescan: one dirty bit per 64-key tile
  const unsigned char* mrow = mask + ((size_t)b * CS + qw + (lane >> 2)) * CS + (lane & 3) * 16;
  unsigned int dirtybits = 0;
#pragma unroll 4
  for (int kt = 0; kt < 32; ++kt) {
    const uint4 mv = *reinterpret_cast<const uint4*>(mrow + kt * 64);
    if (__ballot((mv.x | mv.y | mv.z | mv.w) != 0)) dirtybits |= (1u << kt);
  }

  u16x8 kreg[8];
  auto loadK = [&](int kt) {
    const unsigned short* p = kbase + (size_t)kt * 4096;
#pragma unroll
    for (int f = 0; f < 8; ++f) kreg[f] = *reinterpret_cast<const u16x8*>(p + f * 512);
  };
  auto qk = [&](f32x4 (&sf)[4]) {
#pragma unroll
    for (int g = 0; g < 4; ++g) {
      f32x4 a = {0.f, 0.f, 0.f, 0.f};
      a = mfma16(bc8(kreg[2 * g]), aq0, a);
      a = mfma16(bc8(kreg[2 * g + 1]), aq1, a);
      sf[g] = a;
    }
  };
  const unsigned char* mq = mask + ((size_t)b * CS + qw + fr) * CS + fc * 4;
  auto maskfix = [&](f32x4 (&sf)[4], int kt) {
#pragma unroll
    for (int g = 0; g < 4; ++g) {
      const uchar4 m4 = *reinterpret_cast<const uchar4*>(mq + kt * 64 + g * 16);
      if (m4.x) sf[g][0] = NEGV;
      if (m4.y) sf[g][1] = NEGV;
      if (m4.z) sf[g][2] = NEGV;
      if (m4.w) sf[g][3] = NEGV;
    }
  };

  f32x4 o[4] = {};
  u16x8 vreg[8];
  auto loadV = [&](int kt) {
    const unsigned short* p = vbase + (size_t)kt * 4096;
#pragma unroll
    for (int f = 0; f < 8; ++f) vreg[f] = *reinterpret_cast<const u16x8*>(p + f * 512);
  };

  float* wrow = attnw + ((size_t)bh * CS + qw + fr) * CS + fc * 4;

  loadK(0);
  for (int kt = 0; kt < 32; ++kt) {
    loadV(kt);  // issued early; consumed after QK+softmax latency

    f32x4 sf[4];
    qk(sf);
    loadK(kt + 1 < 32 ? kt + 1 : 0);
    if ((dirtybits >> kt) & 1u) maskfix(sf, kt);

    // normalized weights (per-lane scalar linv — all 16 values are row q=fr)
#pragma unroll
    for (int g = 0; g < 4; ++g)
#pragma unroll
      for (int r = 0; r < 4; ++r) sf[g][r] = exp2f(sf[g][r]) * linv;

    // direct attnw store: lane writes its 4 contiguous keys per g (full 64B lines)
#pragma unroll
    for (int g = 0; g < 4; ++g)
      __builtin_nontemporal_store(sf[g], reinterpret_cast<f32x4*>(wrow + kt * 64 + g * 16));

    // PV A-frags packed in-register (slot s=fc*8+z holds k32=16*(z>>2)+fc*4+(z&3))
    bf16x8 pa[2];
#pragma unroll
    for (int c = 0; c < 2; ++c) {
      unsigned int w0, w1, w2, w3;
      asm("v_cvt_pk_bf16_f32 %0, %1, %2" : "=v"(w0) : "v"(sf[2 * c][0]), "v"(sf[2 * c][1]));
      asm("v_cvt_pk_bf16_f32 %0, %1, %2" : "=v"(w1) : "v"(sf[2 * c][2]), "v"(sf[2 * c][3]));
      asm("v_cvt_pk_bf16_f32 %0, %1, %2" : "=v"(w2) : "v"(sf[2 * c + 1][0]), "v"(sf[2 * c + 1][1]));
      asm("v_cvt_pk_bf16_f32 %0, %1, %2" : "=v"(w3) : "v"(sf[2 * c + 1][2]), "v"(sf[2 * c + 1][3]));
      uint4 uw = {w0, w1, w2, w3};
      pa[c] = __builtin_bit_cast(bf16x8, uw);
    }
#pragma unroll
    for (int g = 0; g < 4; ++g) o[g] = mfma16(pa[0], bc8(vreg[g]), o[g]);
#pragma unroll
    for (int g = 0; g < 4; ++g) o[g] = mfma16(pa[1], bc8(vreg[4 + g]), o[g]);
  }

  // epilogue: o[g][r] = O[q = fc*4+r][d = g*16+fr] -> attn_pre [b][s][h][dk]
#pragma unroll
  for (int g = 0; g < 4; ++g)
#pragma unroll
    for (int r = 0; r < 4; ++r) {
      const int q = qw + fc * 4 + r;
      attn_pre[(((size_t)b * CS + q) * CH + hh) * CDK + g * 16 + fr] = f2bf(o[g][r]);
    }
}

// ---------------------------------------------------------------- launch
extern "C" void kernel_launch(void* const* d_in, const int* in_sizes, int n_in,
                              void* d_out, int out_size, void* d_ws, size_t ws_size,
                              hipStream_t stream) {
  (void)in_sizes; (void)n_in; (void)out_size; (void)ws_size;

  const float* Qf = (const float*)d_in[0];
  const float* Kf = (const float*)d_in[1];
  const float* Vf = (const float*)d_in[2];
  const unsigned char* mask = (const unsigned char*)d_in[3];
  const float* WQw = (const float*)d_in[4];
  const float* WQb = (const float*)d_in[5];
  const float* WKw = (const float*)d_in[6];
  const float* WKb = (const float*)d_in[7];
  const float* WVw = (const float*)d_in[8];
  const float* WVb = (const float*)d_in[9];
  const float* fcw = (const float*)d_in[10];
  const float* fcb = (const float*)d_in[11];

  float* out0 = (float*)d_out;
  float* attnw = out0 + (size_t)CB * CS * CD;  // attn_weights region

  // workspace layout (56 MB used)
  char* w = (char*)d_ws;
  unsigned short* Qb = (unsigned short*)(w);
  unsigned short* Kb = (unsigned short*)(w + 8388608);
  unsigned short* Vb = (unsigned short*)(w + 2 * 8388608);
  unsigned short* Wqb = (unsigned short*)(w + 3 * 8388608);
  unsigned short* Wkb = Wqb + 1048576;
  unsigned short* Wvb = Wkb + 1048576;
  unsigned short* Wfb = Wvb + 1048576;
  unsigned short* qhp = (unsigned short*)(w + 3 * 8388608 + 4 * 2097152);
  unsigned short* kTp = qhp + 4194304;
  unsigned short* vTp = kTp + 4194304;
  unsigned short* apre = Qb;           // alias: Qb dead after q projection
  float* lsum_ws = (float*)Kb;         // alias: Kb dead after gemm_qkv (1 MB)

  const int NELEM4 = (CB * CS * CD) / 4;  // 1048576
  const int WELEM4 = (CD * CD) / 4;       // 262144

  CvtArgs ca;
  ca.src[0] = Qf;  ca.dst[0] = Qb;  ca.n4[0] = NELEM4;
  ca.src[1] = Kf;  ca.dst[1] = Kb;  ca.n4[1] = NELEM4;
  ca.src[2] = Vf;  ca.dst[2] = Vb;  ca.n4[2] = NELEM4;
  ca.src[3] = WQw; ca.dst[3] = Wqb; ca.n4[3] = WELEM4;
  ca.src[4] = WKw; ca.dst[4] = Wkb; ca.n4[4] = WELEM4;
  ca.src[5] = WVw; ca.dst[5] = Wvb; ca.n4[5] = WELEM4;
  ca.src[6] = fcw; ca.dst[6] = Wfb; ca.n4[6] = WELEM4;
  cvt_all<<<dim3(512, 7), 256, 0, stream>>>(ca);

  QKVArgs qa;
  qa.X[0] = Qb;  qa.W[0] = Wqb; qa.bias[0] = WQb; qa.out[0] = qhp; qa.osc[0] = QSCALE;
  qa.X[1] = Kb;  qa.W[1] = Wkb; qa.bias[1] = WKb; qa.out[1] = kTp; qa.osc[1] = 1.0f;
  qa.X[2] = Vb;  qa.W[2] = Wvb; qa.bias[2] = WVb; qa.out[2] = vTp; qa.osc[2] = 1.0f;
  gemm_qkv<<<dim3(CD / 128, (CB * CS) / 128, 3), 256, 0, stream>>>(qa);

  attn_pass1<<<dim3(4096), 256, 0, stream>>>(qhp, kTp, mask, lsum_ws);
  attn_pass2<<<dim3(1024), 256, 0, stream>>>(qhp, kTp, vTp, mask, lsum_ws, attnw, apre);

  gemm_fc<<<dim3(CD / 64, (CB * CS) / 128), 256, 0, stream>>>(apre, Wfb, fcb, out0);
}

// Round 9
// 285.989 us; speedup vs baseline: 1.3209x; 1.3209x over previous
//
#include <hip/hip_runtime.h>
#include <cstdint>
#include <cstddef>

// Problem constants (match reference)
constexpr int CB = 2;      // batch
constexpr int CS = 2048;   // seq
constexpr int CD = 1024;   // model dim
constexpr int CH = 16;     // heads
constexpr int CDK = 64;    // head dim
constexpr float NEGV = -1000000000.0f;
// q pre-scale: (1/sqrt(DK)) / ln2  -> softmax computed via exp2 (HW op):
// exp(q.k/8) == exp2(q.k * QSCALE) with QSCALE folded into the q projection.
constexpr float QSCALE = 0.18033688011112042f;

typedef __bf16 bf16x8 __attribute__((ext_vector_type(8)));
typedef float f32x4 __attribute__((ext_vector_type(4)));
typedef unsigned short u16x8 __attribute__((ext_vector_type(8)));
typedef unsigned short u16x4 __attribute__((ext_vector_type(4)));

static __device__ __forceinline__ unsigned short f2bf(float x) {
  unsigned int u = __float_as_uint(x);
  u += 0x7fffu + ((u >> 16) & 1u);   // round-to-nearest-even
  return (unsigned short)(u >> 16);
}
static __device__ __forceinline__ bf16x8 bc8(u16x8 u) {
  return __builtin_bit_cast(bf16x8, u);
}
static __device__ __forceinline__ f32x4 mfma16(bf16x8 a, bf16x8 b, f32x4 c) {
  return __builtin_amdgcn_mfma_f32_16x16x32_bf16(a, b, c, 0, 0, 0);
}

// ---------------------------------------------------------------- cvt f32->bf16 (all 7 tensors, one launch)
struct CvtArgs {
  const float* src[7];
  unsigned short* dst[7];
  int n4[7];
};

__global__ __launch_bounds__(256) void cvt_all(CvtArgs a) {
  const int r = blockIdx.y;
  const float* __restrict__ in = a.src[r];
  unsigned short* __restrict__ out = a.dst[r];
  const int n4 = a.n4[r];
  const int stride = gridDim.x * 256;
  for (int i = blockIdx.x * 256 + threadIdx.x; i < n4; i += stride) {
    float4 v = reinterpret_cast<const float4*>(in)[i];
    u16x4 o;
    o[0] = f2bf(v.x); o[1] = f2bf(v.y); o[2] = f2bf(v.z); o[3] = f2bf(v.w);
    reinterpret_cast<u16x4*>(out)[i] = o;
  }
}

// ---------------------------------------------------------------- GEMM core (m97 recipe, templated BN)
// BM=128, BN in {64,128}, BK=32, 4 waves. global_load_lds(16B) staging into
// linear LDS; SOURCE 16B-slot XOR-swizzled (rule 21) matching the frag-read
// swizzle. One barrier per K-step, double-buffered.
// X[M,K], W[N,K] bf16 row-major (NT). K=1024 fixed.
constexpr int GK = 1024, GNT = GK / 32;

struct QKVArgs {
  const unsigned short* X[3];
  const unsigned short* W[3];
  const float* bias[3];
  unsigned short* out[3];
  float osc[3];
};

template <int BN, typename EPI>
__device__ __forceinline__ void gemm_body(const unsigned short* __restrict__ X,
                                          const unsigned short* __restrict__ Wt,
                                          EPI epi) {
  __shared__ unsigned short lA[2][128 * 32];
  __shared__ unsigned short lB[2][BN * 32];
  const int tid = threadIdx.x, lane = tid & 63, wid = tid >> 6;
  const int fr = lane & 15, fc = lane >> 4;
  const int mbase = blockIdx.y * 128, nbase = blockIdx.x * BN;
  const int wm = (wid & 1) * 64, wn = (wid >> 1) * (BN / 2);

  // per-wave staging: contiguous 1KB LDS chunks (16 rows x 64B), lane l covers
  // row l>>2, 16B slot (l&3) XOR-swizzled at the SOURCE (read applies same XOR).
  const int srow = lane >> 2;
  const int sslot = (lane & 3) ^ (srow & 3);
  const int cA = wid * 2;  // wave's A chunk base (2 chunks of 16 rows)
  const unsigned short* a0 = X + (size_t)(mbase + cA * 16 + srow) * GK + sslot * 8;
  const unsigned short* b0;
  if constexpr (BN == 128) b0 = Wt + (size_t)(nbase + cA * 16 + srow) * GK + sslot * 8;
  else                     b0 = Wt + (size_t)(nbase + wid * 16 + srow) * GK + sslot * 8;

  auto stage = [&](int buf, int k0) {
#pragma unroll
    for (int c = 0; c < 2; ++c)
      __builtin_amdgcn_global_load_lds(
          (const __attribute__((address_space(1))) void*)(a0 + (size_t)c * 16 * GK + k0),
          (__attribute__((address_space(3))) void*)((char*)&lA[buf][0] + (cA + c) * 1024), 16, 0, 0);
    if constexpr (BN == 128) {
#pragma unroll
      for (int c = 0; c < 2; ++c)
        __builtin_amdgcn_global_load_lds(
            (const __attribute__((address_space(1))) void*)(b0 + (size_t)c * 16 * GK + k0),
            (__attribute__((address_space(3))) void*)((char*)&lB[buf][0] + (cA + c) * 1024), 16, 0, 0);
    } else {
      __builtin_amdgcn_global_load_lds(
          (const __attribute__((address_space(1))) void*)(b0 + k0),
          (__attribute__((address_space(3))) void*)((char*)&lB[buf][0] + wid * 1024), 16, 0, 0);
    }
  };

  constexpr int NJ = BN / 32;
  f32x4 acc[4][NJ] = {};
  stage(0, 0);
  __syncthreads();
  for (int t = 0; t < GNT; ++t) {
    if (t + 1 < GNT) stage((t + 1) & 1, (t + 1) * 32);
    const int buf = t & 1;
    bf16x8 af[4], bfv[NJ];
#pragma unroll
    for (int i = 0; i < 4; ++i) {
      const int row = wm + i * 16 + fr;
      af[i] = bc8(*reinterpret_cast<const u16x8*>(&lA[buf][row * 32 + ((fc ^ (row & 3)) * 8)]));
    }
#pragma unroll
    for (int j = 0; j < NJ; ++j) {
      const int row = wn + j * 16 + fr;
      bfv[j] = bc8(*reinterpret_cast<const u16x8*>(&lB[buf][row * 32 + ((fc ^ (row & 3)) * 8)]));
    }
#pragma unroll
    for (int i = 0; i < 4; ++i)
#pragma unroll
      for (int j = 0; j < NJ; ++j)
        acc[i][j] = mfma16(af[i], bfv[j], acc[i][j]);
    __syncthreads();
  }

#pragma unroll
  for (int j = 0; j < NJ; ++j) {
    const int colb = nbase + wn + j * 16 + fr;
#pragma unroll
    for (int i = 0; i < 4; ++i) {
#pragma unroll
      for (int r = 0; r < 4; ++r) {
        const int rowb = mbase + wm + i * 16 + fc * 4 + r;
        epi(rowb, colb, acc[i][j][r]);
      }
    }
  }
}

// Output layouts:
//  z=0 q : bf16 [bh][s][dk], pre-scaled by QSCALE
//  z=1 k : bf16 frag-tiled [bh][kt][g*2+half][lane*8+z]  (QK A-frags: rows=keys,
//          slots=dk, lane = fr2+16*fc2, identical A/B frag layout)
//  z=2 v : bf16 slot-permuted frag tiles [bh][kt][c*4+g][lane*8+zv] matching the
//          in-register P packing: within a 32-key chunk c, slot s=fc*8+z holds
//          key k32 = 16*(z>>2) + fc*4 + (z&3); lane = (d&15) + 16*fc.
__global__ __launch_bounds__(256, 3) void gemm_qkv(QKVArgs a) {
  const int z = blockIdx.z;
  const float* bias = a.bias[z];
  unsigned short* out = a.out[z];
  const float osc = a.osc[z];
  gemm_body<128>(a.X[z], a.W[z], [&](int rowb, int colb, float av) {
    const float v = (av + bias[colb]) * osc;
    const int bb = rowb >> 11, sr = rowb & (CS - 1);
    const int hh = colb >> 6, cc = colb & (CDK - 1);
    const size_t bh = (size_t)bb * CH + hh;
    if (z == 0) {
      out[(bh * CS + sr) * CDK + cc] = f2bf(v);
    } else if (z == 1) {
      const int kt = sr >> 6, ww = sr & 63, g = ww >> 4, fr2 = ww & 15;
      const int half = cc >> 5, fc2 = (cc >> 3) & 3, zz = cc & 7;
      out[(bh * 256 + kt * 8 + g * 2 + half) * 512 + (fc2 * 16 + fr2) * 8 + zz] = f2bf(v);
    } else {
      const int kt = sr >> 6, kk = sr & 63;
      const int c = kk >> 5, k32 = kk & 31;
      const int fcv = (k32 >> 2) & 3;              // slot group
      const int zv = ((k32 >> 4) << 2) | (k32 & 3);  // element within lane
      const int g = cc >> 4, fr2 = cc & 15;
      out[(bh * 256 + kt * 8 + c * 4 + g) * 512 + (fr2 + 16 * fcv) * 8 + zv] = f2bf(v);
    }
  });
}

__global__ __launch_bounds__(256) void gemm_fc(const unsigned short* __restrict__ X,
                                               const unsigned short* __restrict__ Wt,
                                               const float* __restrict__ bias,
                                               float* __restrict__ out) {
  gemm_body<64>(X, Wt, [&](int rowb, int colb, float av) {
    out[(size_t)rowb * CD + colb] = av + bias[colb];
  });
}

// ---------------------------------------------------------------- fused attention
// Barrier-free, LDS-free, SWAPPED QK^T, 32 queries per wave. One block (4
// independent waves) per (b,h,128q tile); wave owns 32 queries as TWO Q
// B-fragments (rows q..q+15, q+16..q+31) that share every kreg/vreg load ->
// K/V L2 traffic of the 16q version halves, per-iteration ILP doubles.
// mfma(K_frag, Q_frag) puts P row-local: lane (fr,fc) reg (g,r) =
// P[q=fr][k = g*16 + fc*4 + r], so the denominator is a per-lane scalar
// (2 shuffles at the end), attnw is stored directly (4 nontemporal f32x4 per
// g), and the PV A-frag is packed in-register with v_cvt_pk_bf16_f32 against
// slot-permuted V tiles. Softmax: no max subtraction (scores ~N(0,1), f32
// exp2 headroom >120 units; masked entries exp2(-1e9)=0, same as reference
// underflow), exp2 with 1/ln2 folded into the q projection.
__global__ __launch_bounds__(256, 2) void attn_fused(const unsigned short* __restrict__ qh,
                                                     const unsigned short* __restrict__ kT,
                                                     const unsigned short* __restrict__ vT,
                                                     const unsigned char* __restrict__ mask,
                                                     float* __restrict__ attnw,
                                                     unsigned short* __restrict__ attn_pre) {
  const int tid = threadIdx.x, lane = tid & 63, wid = tid >> 6;
  // bijective XCD swizzle: 512 blocks, each XCD gets 64 consecutive swz = 4 heads
  const int bid = blockIdx.x;
  const int swz = (bid & 7) * 64 + (bid >> 3);
  const int qt = swz & 15, hh = (swz >> 4) & 15, b = swz >> 8;
  const int bh = b * CH + hh;
  const int qwA = qt * 128 + wid * 32;
  const int qwB = qwA + 16;
  const int fr = lane & 15, fc = lane >> 4;

  // q fragments (B-operand) for both halves: row = fr (query), dk = fc*8..
  const unsigned short* qpA = qh + ((size_t)bh * CS + qwA + fr) * CDK + fc * 8;
  const bf16x8 aqA0 = bc8(*reinterpret_cast<const u16x8*>(qpA));
  const bf16x8 aqA1 = bc8(*reinterpret_cast<const u16x8*>(qpA + 32));
  const unsigned short* qpB = qpA + 16 * CDK;
  const bf16x8 aqB0 = bc8(*reinterpret_cast<const u16x8*>(qpB));
  const bf16x8 aqB1 = bc8(*reinterpret_cast<const u16x8*>(qpB + 32));

  const unsigned short* kbase = kT + (size_t)bh * 131072 + lane * 8;
  const unsigned short* vbase = vT + (size_t)bh * 131072 + lane * 8;

  // ---------------- mask prescan: one dirty bit per 64-key tile (32 q rows)
  const unsigned char* mrowA = mask + ((size_t)b * CS + qwA + (lane >> 2)) * CS + (lane & 3) * 16;
  const unsigned char* mrowB = mrowA + (size_t)16 * CS;
  unsigned int dirtybits = 0;
#pragma unroll 4
  for (int kt = 0; kt < 32; ++kt) {
    const uint4 m0 = *reinterpret_cast<const uint4*>(mrowA + kt * 64);
    const uint4 m1 = *reinterpret_cast<const uint4*>(mrowB + kt * 64);
    if (__ballot((m0.x | m0.y | m0.z | m0.w | m1.x | m1.y | m1.z | m1.w) != 0))
      dirtybits |= (1u << kt);
  }

  u16x8 kreg[8];
  auto loadK = [&](int kt) {
    const unsigned short* p = kbase + (size_t)kt * 4096;
#pragma unroll
    for (int f = 0; f < 8; ++f) kreg[f] = *reinterpret_cast<const u16x8*>(p + f * 512);
  };
  // swapped QK: A = K (rows=keys), B = Q (rows=queries) -> sf[g][r] = S[k][q=fr]
  auto qk = [&](const bf16x8 b0, const bf16x8 b1, f32x4 (&sf)[4]) {
#pragma unroll
    for (int g = 0; g < 4; ++g) {
      f32x4 a = {0.f, 0.f, 0.f, 0.f};
      a = mfma16(bc8(kreg[2 * g]), b0, a);
      a = mfma16(bc8(kreg[2 * g + 1]), b1, a);
      sf[g] = a;
    }
  };
  // lane's 16 scores per half are row q=fr, keys kt*64 + g*16 + fc*4 + r
  const unsigned char* mqA = mask + ((size_t)b * CS + qwA + fr) * CS + fc * 4;
  const unsigned char* mqB = mqA + (size_t)16 * CS;
  auto maskfix = [&](f32x4 (&sf)[4], int kt, const unsigned char* mq) {
#pragma unroll
    for (int g = 0; g < 4; ++g) {
      const uchar4 m4 = *reinterpret_cast<const uchar4*>(mq + kt * 64 + g * 16);
      if (m4.x) sf[g][0] = NEGV;
      if (m4.y) sf[g][1] = NEGV;
      if (m4.z) sf[g][2] = NEGV;
      if (m4.w) sf[g][3] = NEGV;
    }
  };

  // ---------------- pass 1: denominators (per-lane scalar partials)
  float lsA = 0.f, lsB = 0.f;
  loadK(0);
  for (int kt = 0; kt < 32; ++kt) {
    f32x4 sfA[4], sfB[4];
    qk(aqA0, aqA1, sfA);
    qk(aqB0, aqB1, sfB);
    loadK(kt + 1 < 32 ? kt + 1 : 0);  // prefetch (WAR orders after MFMAs)
    if ((dirtybits >> kt) & 1u) { maskfix(sfA, kt, mqA); maskfix(sfB, kt, mqB); }
#pragma unroll
    for (int g = 0; g < 4; ++g) {
      lsA += (exp2f(sfA[g][0]) + exp2f(sfA[g][1])) + (exp2f(sfA[g][2]) + exp2f(sfA[g][3]));
      lsB += (exp2f(sfB[g][0]) + exp2f(sfB[g][1])) + (exp2f(sfB[g][2]) + exp2f(sfB[g][3]));
    }
  }
  lsA += __shfl_xor(lsA, 16);
  lsA += __shfl_xor(lsA, 32);
  lsB += __shfl_xor(lsB, 16);
  lsB += __shfl_xor(lsB, 32);
  const float linvA = 1.0f / lsA;
  const float linvB = 1.0f / lsB;

  // ---------------- pass 2: weights write + PV (halves share kreg/vreg)
  f32x4 oA[4] = {}, oB[4] = {};
  u16x8 vreg[8];
  auto loadV = [&](int kt) {
    const unsigned short* p = vbase + (size_t)kt * 4096;
#pragma unroll
    for (int f = 0; f < 8; ++f) vreg[f] = *reinterpret_cast<const u16x8*>(p + f * 512);
  };
  float* wrowA = attnw + ((size_t)bh * CS + qwA + fr) * CS + fc * 4;
  float* wrowB = wrowA + (size_t)16 * CS;

  // one half: normalize, store weights, pack PA, accumulate PV
  auto half = [&](f32x4 (&sf)[4], const float linv, float* wrow, f32x4 (&o)[4], int kt) {
#pragma unroll
    for (int g = 0; g < 4; ++g)
#pragma unroll
      for (int r = 0; r < 4; ++r) sf[g][r] = exp2f(sf[g][r]) * linv;
#pragma unroll
    for (int g = 0; g < 4; ++g)
      __builtin_nontemporal_store(sf[g], reinterpret_cast<f32x4*>(wrow + kt * 64 + g * 16));
    bf16x8 pa[2];
#pragma unroll
    for (int c = 0; c < 2; ++c) {
      unsigned int w0, w1, w2, w3;
      asm("v_cvt_pk_bf16_f32 %0, %1, %2" : "=v"(w0) : "v"(sf[2 * c][0]), "v"(sf[2 * c][1]));
      asm("v_cvt_pk_bf16_f32 %0, %1, %2" : "=v"(w1) : "v"(sf[2 * c][2]), "v"(sf[2 * c][3]));
      asm("v_cvt_pk_bf16_f32 %0, %1, %2" : "=v"(w2) : "v"(sf[2 * c + 1][0]), "v"(sf[2 * c + 1][1]));
      asm("v_cvt_pk_bf16_f32 %0, %1, %2" : "=v"(w3) : "v"(sf[2 * c + 1][2]), "v"(sf[2 * c + 1][3]));
      uint4 uw = {w0, w1, w2, w3};
      pa[c] = __builtin_bit_cast(bf16x8, uw);
    }
#pragma unroll
    for (int g = 0; g < 4; ++g) o[g] = mfma16(pa[0], bc8(vreg[g]), o[g]);
#pragma unroll
    for (int g = 0; g < 4; ++g) o[g] = mfma16(pa[1], bc8(vreg[4 + g]), o[g]);
  };

  loadK(0);
  for (int kt = 0; kt < 32; ++kt) {
    loadV(kt);  // issued early; consumed after QK+softmax latency

    f32x4 sfA[4], sfB[4];
    qk(aqA0, aqA1, sfA);
    qk(aqB0, aqB1, sfB);
    loadK(kt + 1 < 32 ? kt + 1 : 0);
    if ((dirtybits >> kt) & 1u) { maskfix(sfA, kt, mqA); maskfix(sfB, kt, mqB); }

    half(sfA, linvA, wrowA, oA, kt);
    half(sfB, linvB, wrowB, oB, kt);
  }

  // epilogue: o[g][r] = O[q = fc*4+r][d = g*16+fr] -> attn_pre [b][s][h][dk]
#pragma unroll
  for (int g = 0; g < 4; ++g)
#pragma unroll
    for (int r = 0; r < 4; ++r) {
      const int qA = qwA + fc * 4 + r;
      attn_pre[(((size_t)b * CS + qA) * CH + hh) * CDK + g * 16 + fr] = f2bf(oA[g][r]);
      const int qB = qwB + fc * 4 + r;
      attn_pre[(((size_t)b * CS + qB) * CH + hh) * CDK + g * 16 + fr] = f2bf(oB[g][r]);
    }
}

// ---------------------------------------------------------------- launch
extern "C" void kernel_launch(void* const* d_in, const int* in_sizes, int n_in,
                              void* d_out, int out_size, void* d_ws, size_t ws_size,
                              hipStream_t stream) {
  (void)in_sizes; (void)n_in; (void)out_size; (void)ws_size;

  const float* Qf = (const float*)d_in[0];
  const float* Kf = (const float*)d_in[1];
  const float* Vf = (const float*)d_in[2];
  const unsigned char* mask = (const unsigned char*)d_in[3];
  const float* WQw = (const float*)d_in[4];
  const float* WQb = (const float*)d_in[5];
  const float* WKw = (const float*)d_in[6];
  const float* WKb = (const float*)d_in[7];
  const float* WVw = (const float*)d_in[8];
  const float* WVb = (const float*)d_in[9];
  const float* fcw = (const float*)d_in[10];
  const float* fcb = (const float*)d_in[11];

  float* out0 = (float*)d_out;
  float* attnw = out0 + (size_t)CB * CS * CD;  // attn_weights region

  // workspace layout (56 MB used)
  char* w = (char*)d_ws;
  unsigned short* Qb = (unsigned short*)(w);
  unsigned short* Kb = (unsigned short*)(w + 8388608);
  unsigned short* Vb = (unsigned short*)(w + 2 * 8388608);
  unsigned short* Wqb = (unsigned short*)(w + 3 * 8388608);
  unsigned short* Wkb = Wqb + 1048576;
  unsigned short* Wvb = Wkb + 1048576;
  unsigned short* Wfb = Wvb + 1048576;
  unsigned short* qhp = (unsigned short*)(w + 3 * 8388608 + 4 * 2097152);
  unsigned short* kTp = qhp + 4194304;
  unsigned short* vTp = kTp + 4194304;
  unsigned short* apre = Qb;  // alias: Qb dead after q projection

  const int NELEM4 = (CB * CS * CD) / 4;  // 1048576
  const int WELEM4 = (CD * CD) / 4;       // 262144

  CvtArgs ca;
  ca.src[0] = Qf;  ca.dst[0] = Qb;  ca.n4[0] = NELEM4;
  ca.src[1] = Kf;  ca.dst[1] = Kb;  ca.n4[1] = NELEM4;
  ca.src[2] = Vf;  ca.dst[2] = Vb;  ca.n4[2] = NELEM4;
  ca.src[3] = WQw; ca.dst[3] = Wqb; ca.n4[3] = WELEM4;
  ca.src[4] = WKw; ca.dst[4] = Wkb; ca.n4[4] = WELEM4;
  ca.src[5] = WVw; ca.dst[5] = Wvb; ca.n4[5] = WELEM4;
  ca.src[6] = fcw; ca.dst[6] = Wfb; ca.n4[6] = WELEM4;
  cvt_all<<<dim3(512, 7), 256, 0, stream>>>(ca);

  QKVArgs qa;
  qa.X[0] = Qb;  qa.W[0] = Wqb; qa.bias[0] = WQb; qa.out[0] = qhp; qa.osc[0] = QSCALE;
  qa.X[1] = Kb;  qa.W[1] = Wkb; qa.bias[1] = WKb; qa.out[1] = kTp; qa.osc[1] = 1.0f;
  qa.X[2] = Vb;  qa.W[2] = Wvb; qa.bias[2] = WVb; qa.out[2] = vTp; qa.osc[2] = 1.0f;
  gemm_qkv<<<dim3(CD / 128, (CB * CS) / 128, 3), 256, 0, stream>>>(qa);

  attn_fused<<<dim3(512), 256, 0, stream>>>(qhp, kTp, vTp, mask, attnw, apre);

  gemm_fc<<<dim3(CD / 64, (CB * CS) / 128), 256, 0, stream>>>(apre, Wfb, fcb, out0);
}

// Round 10
// 256.119 us; speedup vs baseline: 1.4749x; 1.1166x over previous
//
#include <hip/hip_runtime.h>
#include <cstdint>
#include <cstddef>

// Problem constants (match reference)
constexpr int CB = 2;      // batch
constexpr int CS = 2048;   // seq
constexpr int CD = 1024;   // model dim
constexpr int CH = 16;     // heads
constexpr int CDK = 64;    // head dim
constexpr float NEGV = -1000000000.0f;
// q pre-scale: (1/sqrt(DK)) / ln2  -> softmax computed via exp2 (HW op):
// exp(q.k/8) == exp2(q.k * QSCALE) with QSCALE folded into the q projection.
constexpr float QSCALE = 0.18033688011112042f;

typedef __bf16 bf16x8 __attribute__((ext_vector_type(8)));
typedef float f32x4 __attribute__((ext_vector_type(4)));
typedef unsigned short u16x8 __attribute__((ext_vector_type(8)));
typedef unsigned short u16x4 __attribute__((ext_vector_type(4)));

static __device__ __forceinline__ unsigned short f2bf(float x) {
  unsigned int u = __float_as_uint(x);
  u += 0x7fffu + ((u >> 16) & 1u);   // round-to-nearest-even
  return (unsigned short)(u >> 16);
}
static __device__ __forceinline__ bf16x8 bc8(u16x8 u) {
  return __builtin_bit_cast(bf16x8, u);
}
static __device__ __forceinline__ f32x4 mfma16(bf16x8 a, bf16x8 b, f32x4 c) {
  return __builtin_amdgcn_mfma_f32_16x16x32_bf16(a, b, c, 0, 0, 0);
}

// ---------------------------------------------------------------- cvt f32->bf16 (all 7 tensors, one launch)
struct CvtArgs {
  const float* src[7];
  unsigned short* dst[7];
  int n4[7];
};

__global__ __launch_bounds__(256) void cvt_all(CvtArgs a) {
  const int r = blockIdx.y;
  const float* __restrict__ in = a.src[r];
  unsigned short* __restrict__ out = a.dst[r];
  const int n4 = a.n4[r];
  const int stride = gridDim.x * 256;
  for (int i = blockIdx.x * 256 + threadIdx.x; i < n4; i += stride) {
    float4 v = reinterpret_cast<const float4*>(in)[i];
    u16x4 o;
    o[0] = f2bf(v.x); o[1] = f2bf(v.y); o[2] = f2bf(v.z); o[3] = f2bf(v.w);
    reinterpret_cast<u16x4*>(out)[i] = o;
  }
}

// ---------------------------------------------------------------- mask dirty-tile prescan
// One block per (b, 64-row q tile): scans 64 rows x 2048 cols of the bool mask,
// emits one 32-bit word (bit kt = any nonzero in that 64-col tile). attn blocks
// then read ONE word instead of each re-scanning 128KB of mask.
__global__ __launch_bounds__(256) void mask_scan(const unsigned char* __restrict__ mask,
                                                 unsigned int* __restrict__ tab) {
  __shared__ unsigned int w;
  if (threadIdx.x == 0) w = 0;
  __syncthreads();
  const int b = blockIdx.y, qt = blockIdx.x;
  const int t = threadIdx.x;
  const int row = qt * 64 + (t >> 2);
  const unsigned char* p = mask + ((size_t)b * CS + row) * CS + (t & 3) * 512;
  unsigned int local = 0;
#pragma unroll
  for (int i = 0; i < 8; ++i) {  // 8 x 64B spans, each one kt tile
    const uint4* q = reinterpret_cast<const uint4*>(p + i * 64);
    const uint4 a = q[0], b4 = q[1], c = q[2], d = q[3];
    if ((a.x | a.y | a.z | a.w | b4.x | b4.y | b4.z | b4.w |
         c.x | c.y | c.z | c.w | d.x | d.y | d.z | d.w) != 0)
      local |= 1u << ((t & 3) * 8 + i);
  }
  if (local) atomicOr(&w, local);
  __syncthreads();
  if (t == 0) tab[b * 32 + qt] = w;
}

// ---------------------------------------------------------------- GEMM core (m97 recipe, templated BN)
// BM=128, BN in {64,128}, BK=32, 4 waves. global_load_lds(16B) staging into
// linear LDS; SOURCE 16B-slot XOR-swizzled (rule 21) matching the frag-read
// swizzle. One barrier per K-step, double-buffered.
// X[M,K], W[N,K] bf16 row-major (NT). K=1024 fixed.
constexpr int GK = 1024, GNT = GK / 32;

struct QKVArgs {
  const unsigned short* X[3];
  const unsigned short* W[3];
  const float* bias[3];
  unsigned short* out[3];
  float osc[3];
};

template <int BN, typename EPI>
__device__ __forceinline__ void gemm_body(const unsigned short* __restrict__ X,
                                          const unsigned short* __restrict__ Wt,
                                          EPI epi) {
  __shared__ unsigned short lA[2][128 * 32];
  __shared__ unsigned short lB[2][BN * 32];
  const int tid = threadIdx.x, lane = tid & 63, wid = tid >> 6;
  const int fr = lane & 15, fc = lane >> 4;
  const int mbase = blockIdx.y * 128, nbase = blockIdx.x * BN;
  const int wm = (wid & 1) * 64, wn = (wid >> 1) * (BN / 2);

  // per-wave staging: contiguous 1KB LDS chunks (16 rows x 64B), lane l covers
  // row l>>2, 16B slot (l&3) XOR-swizzled at the SOURCE (read applies same XOR).
  const int srow = lane >> 2;
  const int sslot = (lane & 3) ^ (srow & 3);
  const int cA = wid * 2;  // wave's A chunk base (2 chunks of 16 rows)
  const unsigned short* a0 = X + (size_t)(mbase + cA * 16 + srow) * GK + sslot * 8;
  const unsigned short* b0;
  if constexpr (BN == 128) b0 = Wt + (size_t)(nbase + cA * 16 + srow) * GK + sslot * 8;
  else                     b0 = Wt + (size_t)(nbase + wid * 16 + srow) * GK + sslot * 8;

  auto stage = [&](int buf, int k0) {
#pragma unroll
    for (int c = 0; c < 2; ++c)
      __builtin_amdgcn_global_load_lds(
          (const __attribute__((address_space(1))) void*)(a0 + (size_t)c * 16 * GK + k0),
          (__attribute__((address_space(3))) void*)((char*)&lA[buf][0] + (cA + c) * 1024), 16, 0, 0);
    if constexpr (BN == 128) {
#pragma unroll
      for (int c = 0; c < 2; ++c)
        __builtin_amdgcn_global_load_lds(
            (const __attribute__((address_space(1))) void*)(b0 + (size_t)c * 16 * GK + k0),
            (__attribute__((address_space(3))) void*)((char*)&lB[buf][0] + (cA + c) * 1024), 16, 0, 0);
    } else {
      __builtin_amdgcn_global_load_lds(
          (const __attribute__((address_space(1))) void*)(b0 + k0),
          (__attribute__((address_space(3))) void*)((char*)&lB[buf][0] + wid * 1024), 16, 0, 0);
    }
  };

  constexpr int NJ = BN / 32;
  f32x4 acc[4][NJ] = {};
  stage(0, 0);
  __syncthreads();
  for (int t = 0; t < GNT; ++t) {
    if (t + 1 < GNT) stage((t + 1) & 1, (t + 1) * 32);
    const int buf = t & 1;
    bf16x8 af[4], bfv[NJ];
#pragma unroll
    for (int i = 0; i < 4; ++i) {
      const int row = wm + i * 16 + fr;
      af[i] = bc8(*reinterpret_cast<const u16x8*>(&lA[buf][row * 32 + ((fc ^ (row & 3)) * 8)]));
    }
#pragma unroll
    for (int j = 0; j < NJ; ++j) {
      const int row = wn + j * 16 + fr;
      bfv[j] = bc8(*reinterpret_cast<const u16x8*>(&lB[buf][row * 32 + ((fc ^ (row & 3)) * 8)]));
    }
#pragma unroll
    for (int i = 0; i < 4; ++i)
#pragma unroll
      for (int j = 0; j < NJ; ++j)
        acc[i][j] = mfma16(af[i], bfv[j], acc[i][j]);
    __syncthreads();
  }

#pragma unroll
  for (int j = 0; j < NJ; ++j) {
    const int colb = nbase + wn + j * 16 + fr;
#pragma unroll
    for (int i = 0; i < 4; ++i) {
#pragma unroll
      for (int r = 0; r < 4; ++r) {
        const int rowb = mbase + wm + i * 16 + fc * 4 + r;
        epi(rowb, colb, acc[i][j][r]);
      }
    }
  }
}

// Output layouts:
//  z=0 q : bf16 [bh][s][dk], pre-scaled by QSCALE
//  z=1 k : bf16 frag-tiled [bh][kt][g*2+half][lane*8+z]  (QK A-frags: rows=keys,
//          slots=dk, lane = fr2+16*fc2, identical A/B frag layout)
//  z=2 v : bf16 slot-permuted frag tiles [bh][kt][c*4+g][lane*8+zv] matching the
//          in-register P packing: within a 32-key chunk c, slot s=fc*8+z holds
//          key k32 = 16*(z>>2) + fc*4 + (z&3); lane = (d&15) + 16*fc.
__global__ __launch_bounds__(256, 3) void gemm_qkv(QKVArgs a) {
  const int z = blockIdx.z;
  const float* bias = a.bias[z];
  unsigned short* out = a.out[z];
  const float osc = a.osc[z];
  gemm_body<128>(a.X[z], a.W[z], [&](int rowb, int colb, float av) {
    const float v = (av + bias[colb]) * osc;
    const int bb = rowb >> 11, sr = rowb & (CS - 1);
    const int hh = colb >> 6, cc = colb & (CDK - 1);
    const size_t bh = (size_t)bb * CH + hh;
    if (z == 0) {
      out[(bh * CS + sr) * CDK + cc] = f2bf(v);
    } else if (z == 1) {
      const int kt = sr >> 6, ww = sr & 63, g = ww >> 4, fr2 = ww & 15;
      const int half = cc >> 5, fc2 = (cc >> 3) & 3, zz = cc & 7;
      out[(bh * 256 + kt * 8 + g * 2 + half) * 512 + (fc2 * 16 + fr2) * 8 + zz] = f2bf(v);
    } else {
      const int kt = sr >> 6, kk = sr & 63;
      const int c = kk >> 5, k32 = kk & 31;
      const int fcv = (k32 >> 2) & 3;              // slot group
      const int zv = ((k32 >> 4) << 2) | (k32 & 3);  // element within lane
      const int g = cc >> 4, fr2 = cc & 15;
      out[(bh * 256 + kt * 8 + c * 4 + g) * 512 + (fr2 + 16 * fcv) * 8 + zv] = f2bf(v);
    }
  });
}

__global__ __launch_bounds__(256) void gemm_fc(const unsigned short* __restrict__ X,
                                               const unsigned short* __restrict__ Wt,
                                               const float* __restrict__ bias,
                                               float* __restrict__ out) {
  gemm_body<64>(X, Wt, [&](int rowb, int colb, float av) {
    out[(size_t)rowb * CD + colb] = av + bias[colb];
  });
}

// ---------------------------------------------------------------- fused attention
// Barrier-free, LDS-free, SWAPPED QK^T, 16 queries per wave, 4 waves/SIMD.
// One block (4 independent waves) per (b,h,64q tile). mfma(K_frag, Q_frag)
// puts P row-local: lane (fr,fc) reg (g,r) = P[q=fr][k = g*16 + fc*4 + r]:
//  - denominator: per-lane scalar accumulate, 2 shuffles at the end
//  - attnw store: 4 direct nontemporal f32x4 stores (no LDS transpose)
//  - PV A-frag: 8x v_cvt_pk_bf16_f32 in-register against slot-permuted V tiles.
// Dirty-tile bits come precomputed from mask_scan (one scalar load, no per-block
// 128KB mask rescan). Softmax: no max subtraction (scores ~N(0,1), f32 exp2
// headroom >120 units; masked entries exp2(-1e9)=0, same as reference
// underflow), exp2 with 1/ln2 folded into the q projection.
// __launch_bounds__(256,4): cap 128 VGPR -> 4 waves/SIMD (body ~110 VGPR).
__global__ __launch_bounds__(256, 4) void attn_fused(const unsigned short* __restrict__ qh,
                                                     const unsigned short* __restrict__ kT,
                                                     const unsigned short* __restrict__ vT,
                                                     const unsigned char* __restrict__ mask,
                                                     const unsigned int* __restrict__ dirtytab,
                                                     float* __restrict__ attnw,
                                                     unsigned short* __restrict__ attn_pre) {
  const int tid = threadIdx.x, lane = tid & 63, wid = tid >> 6;
  // bijective XCD swizzle: each XCD gets 128 consecutive swz = 4 whole heads
  const int bid = blockIdx.x;
  const int swz = (bid & 7) * 128 + (bid >> 3);
  const int qt = swz & 31, hh = (swz >> 5) & 15, b = swz >> 9;
  const int bh = b * CH + hh;
  const int qw = qt * 64 + wid * 16;
  const int fr = lane & 15, fc = lane >> 4;

  // precomputed dirty bits for this (b, 64-row tile) — wave-uniform scalar
  const unsigned int dirtybits = dirtytab[b * 32 + qt];

  // q fragments (B-operand): row = fr (query), dk = fc*8.. per 32-chunk
  const unsigned short* qp = qh + ((size_t)bh * CS + qw + fr) * CDK + fc * 8;
  const bf16x8 aq0 = bc8(*reinterpret_cast<const u16x8*>(qp));
  const bf16x8 aq1 = bc8(*reinterpret_cast<const u16x8*>(qp + 32));

  const unsigned short* kbase = kT + (size_t)bh * 131072 + lane * 8;
  const unsigned short* vbase = vT + (size_t)bh * 131072 + lane * 8;

  u16x8 kreg[8];
  auto loadK = [&](int kt) {
    const unsigned short* p = kbase + (size_t)kt * 4096;
#pragma unroll
    for (int f = 0; f < 8; ++f) kreg[f] = *reinterpret_cast<const u16x8*>(p + f * 512);
  };
  // swapped QK: A = K (rows=keys), B = Q (rows=queries) -> sf[g][r] = S[k][q=fr]
  auto qk = [&](f32x4 (&sf)[4]) {
    __builtin_amdgcn_s_setprio(1);
#pragma unroll
    for (int g = 0; g < 4; ++g) {
      f32x4 a = {0.f, 0.f, 0.f, 0.f};
      a = mfma16(bc8(kreg[2 * g]), aq0, a);
      a = mfma16(bc8(kreg[2 * g + 1]), aq1, a);
      sf[g] = a;
    }
    __builtin_amdgcn_s_setprio(0);
  };
  // lane's 16 scores are row q=fr, keys kt*64 + g*16 + fc*4 + r (r contiguous)
  const unsigned char* mq = mask + ((size_t)b * CS + qw + fr) * CS + fc * 4;
  auto maskfix = [&](f32x4 (&sf)[4], int kt) {
#pragma unroll
    for (int g = 0; g < 4; ++g) {
      const uchar4 m4 = *reinterpret_cast<const uchar4*>(mq + kt * 64 + g * 16);
      if (m4.x) sf[g][0] = NEGV;
      if (m4.y) sf[g][1] = NEGV;
      if (m4.z) sf[g][2] = NEGV;
      if (m4.w) sf[g][3] = NEGV;
    }
  };

  // ---------------- pass 1: denominator (per-lane scalar partial)
  float lsum = 0.f;
  loadK(0);
  for (int kt = 0; kt < 32; ++kt) {
    f32x4 sf[4];
    qk(sf);
    if (kt + 1 < 32) loadK(kt + 1);  // prefetch (WAR orders after MFMAs)
    if ((dirtybits >> kt) & 1u) maskfix(sf, kt);
#pragma unroll
    for (int g = 0; g < 4; ++g)
      lsum += (exp2f(sf[g][0]) + exp2f(sf[g][1])) + (exp2f(sf[g][2]) + exp2f(sf[g][3]));
  }
  lsum += __shfl_xor(lsum, 16);
  lsum += __shfl_xor(lsum, 32);
  const float linv = 1.0f / lsum;

  // ---------------- pass 2: weights write + PV
  f32x4 o[4] = {};
  u16x8 vreg[8];
  auto loadV = [&](int kt) {
    const unsigned short* p = vbase + (size_t)kt * 4096;
#pragma unroll
    for (int f = 0; f < 8; ++f) vreg[f] = *reinterpret_cast<const u16x8*>(p + f * 512);
  };

  float* wrow = attnw + ((size_t)bh * CS + qw + fr) * CS + fc * 4;

  loadK(0);
  for (int kt = 0; kt < 32; ++kt) {
    loadV(kt);  // issued early; consumed after QK+softmax latency

    f32x4 sf[4];
    qk(sf);
    if (kt + 1 < 32) loadK(kt + 1);
    if ((dirtybits >> kt) & 1u) maskfix(sf, kt);

    // normalized weights (per-lane scalar linv — all 16 values are row q=fr)
#pragma unroll
    for (int g = 0; g < 4; ++g)
#pragma unroll
      for (int r = 0; r < 4; ++r) sf[g][r] = exp2f(sf[g][r]) * linv;

    // direct attnw store: lane writes its 4 contiguous keys per g
#pragma unroll
    for (int g = 0; g < 4; ++g)
      __builtin_nontemporal_store(sf[g], reinterpret_cast<f32x4*>(wrow + kt * 64 + g * 16));

    // PV A-frags packed in-register (slot s=fc*8+z holds k32=16*(z>>2)+fc*4+(z&3))
    bf16x8 pa[2];
#pragma unroll
    for (int c = 0; c < 2; ++c) {
      unsigned int w0, w1, w2, w3;
      asm("v_cvt_pk_bf16_f32 %0, %1, %2" : "=v"(w0) : "v"(sf[2 * c][0]), "v"(sf[2 * c][1]));
      asm("v_cvt_pk_bf16_f32 %0, %1, %2" : "=v"(w1) : "v"(sf[2 * c][2]), "v"(sf[2 * c][3]));
      asm("v_cvt_pk_bf16_f32 %0, %1, %2" : "=v"(w2) : "v"(sf[2 * c + 1][0]), "v"(sf[2 * c + 1][1]));
      asm("v_cvt_pk_bf16_f32 %0, %1, %2" : "=v"(w3) : "v"(sf[2 * c + 1][2]), "v"(sf[2 * c + 1][3]));
      uint4 uw = {w0, w1, w2, w3};
      pa[c] = __builtin_bit_cast(bf16x8, uw);
    }
    __builtin_amdgcn_s_setprio(1);
#pragma unroll
    for (int g = 0; g < 4; ++g) o[g] = mfma16(pa[0], bc8(vreg[g]), o[g]);
#pragma unroll
    for (int g = 0; g < 4; ++g) o[g] = mfma16(pa[1], bc8(vreg[4 + g]), o[g]);
    __builtin_amdgcn_s_setprio(0);
  }

  // epilogue: o[g][r] = O[q = fc*4+r][d = g*16+fr] -> attn_pre [b][s][h][dk]
#pragma unroll
  for (int g = 0; g < 4; ++g)
#pragma unroll
    for (int r = 0; r < 4; ++r) {
      const int q = qw + fc * 4 + r;
      attn_pre[(((size_t)b * CS + q) * CH + hh) * CDK + g * 16 + fr] = f2bf(o[g][r]);
    }
}

// ---------------------------------------------------------------- launch
extern "C" void kernel_launch(void* const* d_in, const int* in_sizes, int n_in,
                              void* d_out, int out_size, void* d_ws, size_t ws_size,
                              hipStream_t stream) {
  (void)in_sizes; (void)n_in; (void)out_size; (void)ws_size;

  const float* Qf = (const float*)d_in[0];
  const float* Kf = (const float*)d_in[1];
  const float* Vf = (const float*)d_in[2];
  const unsigned char* mask = (const unsigned char*)d_in[3];
  const float* WQw = (const float*)d_in[4];
  const float* WQb = (const float*)d_in[5];
  const float* WKw = (const float*)d_in[6];
  const float* WKb = (const float*)d_in[7];
  const float* WVw = (const float*)d_in[8];
  const float* WVb = (const float*)d_in[9];
  const float* fcw = (const float*)d_in[10];
  const float* fcb = (const float*)d_in[11];

  float* out0 = (float*)d_out;
  float* attnw = out0 + (size_t)CB * CS * CD;  // attn_weights region

  // workspace layout (56 MB used)
  char* w = (char*)d_ws;
  unsigned short* Qb = (unsigned short*)(w);
  unsigned short* Kb = (unsigned short*)(w + 8388608);
  unsigned short* Vb = (unsigned short*)(w + 2 * 8388608);
  unsigned short* Wqb = (unsigned short*)(w + 3 * 8388608);
  unsigned short* Wkb = Wqb + 1048576;
  unsigned short* Wvb = Wkb + 1048576;
  unsigned short* Wfb = Wvb + 1048576;
  unsigned short* qhp = (unsigned short*)(w + 3 * 8388608 + 4 * 2097152);
  unsigned short* kTp = qhp + 4194304;
  unsigned short* vTp = kTp + 4194304;
  unsigned short* apre = Qb;                 // alias: Qb dead after q projection
  unsigned int* dirtytab = (unsigned int*)Kb;  // alias: Kb dead after gemm_qkv (256B)

  const int NELEM4 = (CB * CS * CD) / 4;  // 1048576
  const int WELEM4 = (CD * CD) / 4;       // 262144

  CvtArgs ca;
  ca.src[0] = Qf;  ca.dst[0] = Qb;  ca.n4[0] = NELEM4;
  ca.src[1] = Kf;  ca.dst[1] = Kb;  ca.n4[1] = NELEM4;
  ca.src[2] = Vf;  ca.dst[2] = Vb;  ca.n4[2] = NELEM4;
  ca.src[3] = WQw; ca.dst[3] = Wqb; ca.n4[3] = WELEM4;
  ca.src[4] = WKw; ca.dst[4] = Wkb; ca.n4[4] = WELEM4;
  ca.src[5] = WVw; ca.dst[5] = Wvb; ca.n4[5] = WELEM4;
  ca.src[6] = fcw; ca.dst[6] = Wfb; ca.n4[6] = WELEM4;
  cvt_all<<<dim3(512, 7), 256, 0, stream>>>(ca);

  QKVArgs qa;
  qa.X[0] = Qb;  qa.W[0] = Wqb; qa.bias[0] = WQb; qa.out[0] = qhp; qa.osc[0] = QSCALE;
  qa.X[1] = Kb;  qa.W[1] = Wkb; qa.bias[1] = WKb; qa.out[1] = kTp; qa.osc[1] = 1.0f;
  qa.X[2] = Vb;  qa.W[2] = Wvb; qa.bias[2] = WVb; qa.out[2] = vTp; qa.osc[2] = 1.0f;
  gemm_qkv<<<dim3(CD / 128, (CB * CS) / 128, 3), 256, 0, stream>>>(qa);

  // dirty-tile table AFTER gemm_qkv (dirtytab aliases Kb, gemm input)
  mask_scan<<<dim3(32, CB), 256, 0, stream>>>(mask, dirtytab);

  attn_fused<<<dim3(1024), 256, 0, stream>>>(qhp, kTp, vTp, mask, dirtytab, attnw, apre);

  gemm_fc<<<dim3(CD / 64, (CB * CS) / 128), 256, 0, stream>>>(apre, Wfb, fcb, out0);
}